// Round 6
// baseline (459.420 us; speedup 1.0000x reference)
//
#include <hip/hip_runtime.h>
#include <math.h>

#define EPS_BN 1e-5

namespace {

constexpr double CNT1 = 4096.0 * 1024.0;  // layer1 BN count: B*32*32
constexpr double CNT2 = 4096.0 * 256.0;   // layer2 BN count: B*16*16

// workspace layout (bytes). Required ws >= ~137 MiB.
constexpr size_t OFF_H1 = 0;            // [4096,256px,16ci] bf16 = 32 MiB
constexpr size_t OFF_Y1 = 67108864;     // [4096,1024px,8ch] f16 = 64 MiB (dies after l1_out)
constexpr size_t OFF_Y2 = 67108864;     // [4096,16,16,16] f32 = 64 MiB (aliases Y1)
constexpr size_t OFF_H2 = 0;            // [4096,2048] bf16 (reuses h1 after conv2)
constexpr size_t OFF_A1 = 33554432;     // [4096,512] bf16
constexpr size_t OFF_A2 = 41943040;     // [4096,512] f32
constexpr size_t OFF_ST = 134217728;    // BN stats: 96 slots x 64B
constexpr size_t OFF_WB1 = 134283264;   // fc1_w bf16 [512,2048] = 2 MiB
constexpr size_t OFF_WB2 = 136380416;   // fc2_w bf16 [512,512] = 0.5 MiB

#define STG(p, i) (p)[(size_t)(i) * 8]

typedef short bf16x8 __attribute__((ext_vector_type(8)));
typedef float f32x4 __attribute__((ext_vector_type(4)));
typedef _Float16 f16;
typedef _Float16 f16x8 __attribute__((ext_vector_type(8)));

__device__ __forceinline__ short f2bf(float f) {
  unsigned u = __float_as_uint(f);
  u = (u + 0x7fffu + ((u >> 16) & 1u)) >> 16;
  return (short)u;
}

__device__ __forceinline__ float wave_sum(float v) {
#pragma unroll
  for (int o = 32; o > 0; o >>= 1) v += __shfl_down(v, o, 64);
  return v;
}

template <int NV>
__device__ __forceinline__ void block_stats_atomic(const float* s, const float* q,
                                                   double* __restrict__ st) {
  __shared__ float red[4][NV * 2];
  const int lane = threadIdx.x & 63, wid = threadIdx.x >> 6;
#pragma unroll
  for (int c = 0; c < NV; ++c) {
    float sv = wave_sum(s[c]);
    float qv = wave_sum(q[c]);
    if (lane == 0) { red[wid][2 * c] = sv; red[wid][2 * c + 1] = qv; }
  }
  __syncthreads();
  if (threadIdx.x < NV * 2) {
    float v = red[0][threadIdx.x] + red[1][threadIdx.x] + red[2][threadIdx.x] +
              red[3][threadIdx.x];
    unsafeAtomicAdd(st + (size_t)threadIdx.x * 8, (double)v);
  }
}

// ---------------- layer 1: conv 3x3, 3->8, on 32x32, pad 1 -------------------
__device__ __forceinline__ void conv1_stage_img(const float* __restrict__ xp,
                                                float* xs, int tid) {
  for (int i = tid; i < 3072; i += 256) {
    int ci = i >> 10, r = (i >> 5) & 31, c = i & 31;
    xs[ci * 1156 + (r + 1) * 34 + (c + 1)] = xp[i];
  }
}

__device__ __forceinline__ void conv1_compute_rows(const float* xs,
                                                   const float* wk, int tx,
                                                   int ty, float acc[4][8]) {
#pragma unroll
  for (int p = 0; p < 4; ++p)
#pragma unroll
    for (int co = 0; co < 8; ++co) acc[p][co] = 0.f;
#pragma unroll
  for (int ci = 0; ci < 3; ++ci)
#pragma unroll
    for (int dy = 0; dy < 3; ++dy)
#pragma unroll
      for (int dx = 0; dx < 3; ++dx) {
        const int j = ci * 9 + dy * 3 + dx;
        float wv[8];
        *(float4*)&wv[0] = *(const float4*)&wk[j * 8];
        *(float4*)&wv[4] = *(const float4*)&wk[j * 8 + 4];
#pragma unroll
        for (int p = 0; p < 4; ++p) {
          float xv = xs[ci * 1156 + (ty + 8 * p + dy) * 34 + (tx + dx)];
#pragma unroll
          for (int co = 0; co < 8; ++co) acc[p][co] += xv * wv[co];
        }
      }
}

// conv1 + raw-y1 stats + y1 f16 NHWC store [n][1024px][8ch].
// 2 images per block (both staged up front), grid 2048.
__global__ __launch_bounds__(256) void k_conv1_y1(
    const float* __restrict__ x, const float* __restrict__ w1,
    f16* __restrict__ y1, double* __restrict__ st1) {
  __shared__ __align__(16) float xs[2][3 * 34 * 34];
  __shared__ __align__(16) float wk[216];
  const int tid = threadIdx.x;
  for (int i = tid; i < 2 * 3 * 34 * 34; i += 256) (&xs[0][0])[i] = 0.f;
  if (tid < 216) wk[(tid % 27) * 8 + tid / 27] = w1[tid];
  __syncthreads();
  const int n0 = blockIdx.x * 2;
  conv1_stage_img(x + (size_t)n0 * 3072, xs[0], tid);
  conv1_stage_img(x + (size_t)(n0 + 1) * 3072, xs[1], tid);
  __syncthreads();
  const int tx = tid & 31, ty = tid >> 5;
  float s[8], q[8];
#pragma unroll
  for (int c = 0; c < 8; ++c) { s[c] = 0.f; q[c] = 0.f; }
#pragma unroll
  for (int img = 0; img < 2; ++img) {
    float acc[4][8];
    conv1_compute_rows(xs[img], wk, tx, ty, acc);
#pragma unroll
    for (int p = 0; p < 4; ++p) {
      f16 hv8[8];
#pragma unroll
      for (int co = 0; co < 8; ++co) {
        float v = acc[p][co];
        s[co] += v; q[co] += v * v;
        hv8[co] = (f16)v;
      }
      const int px = (ty + 8 * p) * 32 + tx;
      *(uint4*)&y1[((size_t)(n0 + img) * 1024 + px) * 8] = *(uint4*)hv8;
    }
  }
  block_stats_atomic<8>(s, q, st1);
}

// xr1 = relu(bn1(y1)) stats; grid-strided NHWC streaming, grid 1024.
__global__ __launch_bounds__(256) void k_xr1_stats(
    const f16* __restrict__ y1, const float* __restrict__ g1,
    const float* __restrict__ b1, const double* __restrict__ st1,
    double* __restrict__ st2) {
  float a1[8], c1[8];
#pragma unroll
  for (int c = 0; c < 8; ++c) {
    double sd = STG(st1, 2 * c), qd = STG(st1, 2 * c + 1);
    double md = sd / CNT1;
    float inv = (float)(1.0 / sqrt(qd / CNT1 - md * md + (double)EPS_BN));
    a1[c] = inv * g1[c];
    c1[c] = b1[c] - (float)md * a1[c];
  }
  const size_t base = (size_t)blockIdx.x * 4096 + threadIdx.x;
  float s[8], q[8];
#pragma unroll
  for (int c = 0; c < 8; ++c) { s[c] = 0.f; q[c] = 0.f; }
#pragma unroll
  for (int k = 0; k < 16; ++k) {
    f16x8 v = *(const f16x8*)&y1[(base + (size_t)k * 256) * 8];
#pragma unroll
    for (int c = 0; c < 8; ++c) {
      float xr = fmaxf((float)v[c] * a1[c] + c1[c], 0.f);
      s[c] += xr; q[c] += xr * xr;
    }
  }
  block_stats_atomic<8>(s, q, st2);
}

// y1 NHWC -> BN1+relu -> scale-expand -> BN2+relu -> 2x2 maxpool
// -> h1 bf16 NHWC [img][256px][16c]. 4 images per block, grid 1024.
__global__ __launch_bounds__(256) void k_l1_out(
    const f16* __restrict__ y1, const float* __restrict__ g1,
    const float* __restrict__ b1, const float* __restrict__ dsew,
    const float* __restrict__ bng, const float* __restrict__ bnb,
    const double* __restrict__ st1, const double* __restrict__ st2,
    short* __restrict__ h1) {
  __shared__ float cA1[8], cC1[8], cS2[16], cO2[16];
  const int tid = threadIdx.x;
  if (tid < 16) {
    const int i = tid >> 1, g = tid & 1;
    double sd = STG(st1, 2 * i), qd = STG(st1, 2 * i + 1);
    double md = sd / CNT1;
    float inv1 = (float)(1.0 / sqrt(qd / CNT1 - md * md + (double)EPS_BN));
    float a1 = inv1 * g1[i];
    if (g == 0) { cA1[i] = a1; cC1[i] = b1[i] - (float)md * a1; }
    double s2 = STG(st2, 2 * i), q2 = STG(st2, 2 * i + 1);
    double mx = s2 / CNT1, vx = q2 / CNT1 - mx * mx;
    float w = dsew[i * 2 + g];
    double inv2 = 1.0 / sqrt((double)w * w * vx + (double)EPS_BN);
    cS2[tid] = (float)(w * inv2) * bng[tid];
    cO2[tid] = bnb[tid] - (float)(w * mx * inv2) * bng[tid];
  }
  __syncthreads();
  const int sub = tid >> 6, lane = tid & 63;
  const int n = blockIdx.x * 4 + sub;
#pragma unroll
  for (int w = 0; w < 4; ++w) {
    const int opx = w * 64 + lane, oy = opx >> 4, ox = opx & 15;
    const size_t pbase = ((size_t)n * 1024 + (size_t)(2 * oy) * 32 + 2 * ox) * 8;
    f16x8 vA = *(const f16x8*)&y1[pbase];
    f16x8 vB = *(const f16x8*)&y1[pbase + 8];
    f16x8 vC = *(const f16x8*)&y1[pbase + 256];
    f16x8 vD = *(const f16x8*)&y1[pbase + 264];
    short hv[16];
#pragma unroll
    for (int i = 0; i < 8; ++i) {
      float a1 = cA1[i], c1 = cC1[i];
      float xr0 = fmaxf((float)vA[i] * a1 + c1, 0.f);
      float xr1 = fmaxf((float)vB[i] * a1 + c1, 0.f);
      float xr2 = fmaxf((float)vC[i] * a1 + c1, 0.f);
      float xr3 = fmaxf((float)vD[i] * a1 + c1, 0.f);
#pragma unroll
      for (int g = 0; g < 2; ++g) {
        const int c = 2 * i + g;
        float sc = cS2[c], of = cO2[c];
        float r0 = fmaxf(xr0 * sc + of, 0.f);
        float r1 = fmaxf(xr1 * sc + of, 0.f);
        float r2 = fmaxf(xr2 * sc + of, 0.f);
        float r3 = fmaxf(xr3 * sc + of, 0.f);
        hv[c] = f2bf(fmaxf(fmaxf(r0, r1), fmaxf(r2, r3)));
      }
    }
    uint4* dst = (uint4*)&h1[((size_t)n * 256 + opx) * 16];
    dst[0] = ((uint4*)hv)[0];
    dst[1] = ((uint4*)hv)[1];
  }
}

// ---------------- layer 2 conv via MFMA ---------------------------------
// 4 images per block, grid 1024 (~4 blocks/CU).
__global__ __launch_bounds__(256) void k_conv2_mfma(
    const short* __restrict__ h1, const float* __restrict__ w2,
    float* __restrict__ y2, double* __restrict__ st3) {
  __shared__ short smem[4 * 5184 + 10 * 256];
  __shared__ float red[4][32];
  short* hs = smem;                 // 4 padded images
  short* wt = smem + 4 * 5184;      // [10][16co][16ci], slot 9 stays zero
  const int tid = threadIdx.x, wid = tid >> 6, lane = tid & 63;
  for (int i = tid; i < (4 * 5184 + 10 * 256) / 2; i += 256) ((int*)smem)[i] = 0;
  __syncthreads();
  for (int i = tid; i < 2304; i += 256) {
    const int s = i >> 8, co = (i >> 4) & 15, ci = i & 15;
    wt[i] = f2bf(w2[(co * 16 + ci) * 9 + s]);
  }
  {  // stage 4 images (interior only; borders stay zero)
    const uint4* src = (const uint4*)(h1 + (size_t)blockIdx.x * 4 * 4096);
    for (int ch = tid; ch < 2048; ch += 256) {
      const int im = ch >> 9, j = ch & 511, px = j >> 1, half = j & 1;
      const int r = px >> 4, cc = px & 15;
      *(uint4*)&hs[im * 5184 + ((r + 1) * 18 + (cc + 1)) * 16 + half * 8] =
          src[ch];
    }
  }
  const int c = lane & 15, quad = lane >> 4;
  const int ci0 = (quad & 1) * 8;
  int aoff[5];
#pragma unroll
  for (int p = 0; p < 5; ++p) {
    int s = 2 * p + (quad >> 1);
    if (s > 8) s = 8;  // address clamp; B-frag for that k-half is zero
    const int dy = s / 3, dx = s % 3;
    aoff[p] = (dy * 18 + (c + dx)) * 16 + ci0;
  }
  __syncthreads();
  bf16x8 bf[5];
#pragma unroll
  for (int p = 0; p < 5; ++p) {
    const int s = 2 * p + (quad >> 1);  // s==9 -> wt slot 9 == zeros
    bf[p] = *(const bf16x8*)&wt[s * 256 + c * 16 + ci0];
  }
  float ssum = 0.f, qsum = 0.f;
  const short* hbase = hs + wid * 5184;
  const int img = blockIdx.x * 4 + wid;
  float* yp = y2 + ((size_t)img * 16 + c) * 256 + quad * 4;
  for (int r = 0; r < 16; ++r) {
    f32x4 acc = {0.f, 0.f, 0.f, 0.f};
#pragma unroll
    for (int p = 0; p < 5; ++p) {
      bf16x8 a = *(const bf16x8*)&hbase[r * 288 + aoff[p]];
      acc = __builtin_amdgcn_mfma_f32_16x16x32_bf16(a, bf[p], acc, 0, 0, 0);
    }
    *(float4*)&yp[r * 16] = *(float4*)&acc;
#pragma unroll
    for (int g = 0; g < 4; ++g) { float v = acc[g]; ssum += v; qsum += v * v; }
  }
  // lanes {l, l+16, l+32, l+48} share co = l&15
  ssum += __shfl_down(ssum, 32, 64); ssum += __shfl_down(ssum, 16, 64);
  qsum += __shfl_down(qsum, 32, 64); qsum += __shfl_down(qsum, 16, 64);
  if (lane < 16) { red[wid][lane] = ssum; red[wid][16 + lane] = qsum; }
  __syncthreads();
  if (tid < 32) {
    const int cc = tid & 15, isq = tid >> 4;
    float v = red[0][isq * 16 + cc] + red[1][isq * 16 + cc] +
              red[2][isq * 16 + cc] + red[3][isq * 16 + cc];
    unsafeAtomicAdd(st3 + (size_t)(2 * cc + isq) * 8, (double)v);
  }
}

__global__ __launch_bounds__(256) void k_xr2_stats(
    const float* __restrict__ y2, const float* __restrict__ g2,
    const float* __restrict__ b2, const double* __restrict__ st3,
    double* __restrict__ st4) {
  const int c = blockIdx.x & 15, n0 = (blockIdx.x >> 4) << 4;
  double sd = STG(st3, 2 * c), qd = STG(st3, 2 * c + 1);
  double md = sd / CNT2;
  float m = (float)md;
  float inv = (float)(1.0 / sqrt(qd / CNT2 - md * md + (double)EPS_BN));
  float gg = g2[c], bb = b2[c];
  float s = 0.f, q = 0.f;
#pragma unroll
  for (int k = 0; k < 16; ++k) {
    float v = y2[((size_t)(n0 + k) * 16 + c) * 256 + threadIdx.x];
    float xr = fmaxf((v - m) * inv * gg + bb, 0.f);
    s += xr; q += xr * xr;
  }
  block_stats_atomic<1>(&s, &q, st4 + (size_t)(2 * c) * 8);
}

// y2 -> BN+relu -> scale-expand -> BN+relu -> 2x2 maxpool -> h2 bf16 [4096,2048]
__global__ __launch_bounds__(256) void k_l2_out(
    const float* __restrict__ y2, const float* __restrict__ g2,
    const float* __restrict__ b2, const float* __restrict__ dsew,
    const float* __restrict__ bng, const float* __restrict__ bnb,
    const double* __restrict__ st3, const double* __restrict__ st4,
    short* __restrict__ h2) {
  __shared__ float cS3[16], cO3[16], cS4[32], cO4[32];
  const int tid = threadIdx.x;
  if (tid < 32) {
    const int i = tid >> 1, g = tid & 1;
    double sd = STG(st3, 2 * i), qd = STG(st3, 2 * i + 1);
    double md = sd / CNT2;
    float inv3 = (float)(1.0 / sqrt(qd / CNT2 - md * md + (double)EPS_BN));
    float a3 = inv3 * g2[i];
    if (g == 0) { cS3[i] = a3; cO3[i] = b2[i] - (float)md * a3; }
    double s4 = STG(st4, 2 * i), q4 = STG(st4, 2 * i + 1);
    double mx = s4 / CNT2, vx = q4 / CNT2 - mx * mx;
    float w = dsew[2 * i + g];
    double inv4 = 1.0 / sqrt((double)w * w * vx + (double)EPS_BN);
    cS4[tid] = (float)(w * inv4) * bng[tid];
    cO4[tid] = bnb[tid] - (float)(w * mx * inv4) * bng[tid];
  }
  __syncthreads();
  const int sub = tid >> 6, lane = tid & 63;
  const int n = blockIdx.x * 4 + sub;
  const int px = lane & 7, py = lane >> 3;
#pragma unroll
  for (int i = 0; i < 16; ++i) {
    const size_t base = ((size_t)n * 16 + i) * 256;
    float2 v01 = *(const float2*)&y2[base + (2 * py) * 16 + 2 * px];
    float2 v23 = *(const float2*)&y2[base + (2 * py + 1) * 16 + 2 * px];
    float a3 = cS3[i], c3 = cO3[i];
    float xr0 = fmaxf(v01.x * a3 + c3, 0.f);
    float xr1 = fmaxf(v01.y * a3 + c3, 0.f);
    float xr2 = fmaxf(v23.x * a3 + c3, 0.f);
    float xr3 = fmaxf(v23.y * a3 + c3, 0.f);
#pragma unroll
    for (int g = 0; g < 2; ++g) {
      const int c = 2 * i + g;
      float sc = cS4[c], of = cO4[c];
      float r0 = fmaxf(xr0 * sc + of, 0.f);
      float r1 = fmaxf(xr1 * sc + of, 0.f);
      float r2 = fmaxf(xr2 * sc + of, 0.f);
      float r3 = fmaxf(xr3 * sc + of, 0.f);
      h2[(size_t)n * 2048 + c * 64 + py * 8 + px] =
          f2bf(fmaxf(fmaxf(r0, r1), fmaxf(r2, r3)));
    }
  }
}

// cast fc1_w (512x2048) and fc2_w (512x512) to bf16
__global__ __launch_bounds__(256) void k_cast_w(const float* __restrict__ w1,
                                                const float* __restrict__ w2,
                                                short* __restrict__ o1,
                                                short* __restrict__ o2) {
  const int i = blockIdx.x * 256 + threadIdx.x;
  if (i < 1048576) o1[i] = f2bf(w1[i]);
  else o2[i - 1048576] = f2bf(w2[i - 1048576]);
}

// ------------- FC via MFMA: C[M,512] = act(A[M,K]bf16 @ W[512,K]bf16^T + b) --
template <int K, int RELU, int OUT_BF16>
__global__ __launch_bounds__(256) void k_fc_mfma(
    const short* __restrict__ A, const short* __restrict__ W,
    const float* __restrict__ bias, void* __restrict__ Cv) {
  const int wv = threadIdx.x >> 6, lane = threadIdx.x & 63;
  const int bm = blockIdx.y * 64;
  const int bn = blockIdx.x * 64 + wv * 16;
  const int cl = lane & 15, quad = lane >> 4;
  const short* ap = A + (size_t)(bm + cl) * K + quad * 8;
  const short* bp = W + (size_t)(bn + cl) * K + quad * 8;
  f32x4 acc0 = {0.f, 0.f, 0.f, 0.f}, acc1 = acc0, acc2 = acc0, acc3 = acc0;
#pragma unroll 4
  for (int k0 = 0; k0 < K; k0 += 32) {
    bf16x8 b = *(const bf16x8*)bp;
    bf16x8 a0 = *(const bf16x8*)ap;
    bf16x8 a1 = *(const bf16x8*)(ap + (size_t)16 * K);
    bf16x8 a2 = *(const bf16x8*)(ap + (size_t)32 * K);
    bf16x8 a3 = *(const bf16x8*)(ap + (size_t)48 * K);
    ap += 32; bp += 32;
    acc0 = __builtin_amdgcn_mfma_f32_16x16x32_bf16(a0, b, acc0, 0, 0, 0);
    acc1 = __builtin_amdgcn_mfma_f32_16x16x32_bf16(a1, b, acc1, 0, 0, 0);
    acc2 = __builtin_amdgcn_mfma_f32_16x16x32_bf16(a2, b, acc2, 0, 0, 0);
    acc3 = __builtin_amdgcn_mfma_f32_16x16x32_bf16(a3, b, acc3, 0, 0, 0);
  }
  const float bia = bias[bn + cl];
  f32x4 av[4] = {acc0, acc1, acc2, acc3};
#pragma unroll
  for (int rt = 0; rt < 4; ++rt) {
#pragma unroll
    for (int r = 0; r < 4; ++r) {
      const int row = bm + rt * 16 + quad * 4 + r;
      float v = av[rt][r] + bia;
      if (RELU) v = fmaxf(v, 0.f);
      if (OUT_BF16)
        ((short*)Cv)[(size_t)row * 512 + bn + cl] = f2bf(v);
      else
        ((float*)Cv)[(size_t)row * 512 + bn + cl] = v;
    }
  }
}

// fc3: one wave per row, N=10, K=512, fp32
__global__ __launch_bounds__(256) void k_fc3(const float* __restrict__ A,
                                             const float* __restrict__ W,
                                             const float* __restrict__ b,
                                             float* __restrict__ out) {
  const int wid = threadIdx.x >> 6, lane = threadIdx.x & 63;
  const int row = blockIdx.x * 4 + wid;
  float p[10];
#pragma unroll
  for (int o = 0; o < 10; ++o) p[o] = 0.f;
  const float* a = A + (size_t)row * 512;
#pragma unroll
  for (int jj = 0; jj < 8; ++jj) {
    const int j = lane + jj * 64;
    float av = a[j];
#pragma unroll
    for (int o = 0; o < 10; ++o) p[o] += av * W[o * 512 + j];
  }
#pragma unroll
  for (int o = 0; o < 10; ++o) p[o] = wave_sum(p[o]);
  if (lane == 0) {
#pragma unroll
    for (int o = 0; o < 10; ++o) out[(size_t)row * 10 + o] = p[o] + b[o];
  }
}

}  // namespace

extern "C" void kernel_launch(void* const* d_in, const int* in_sizes, int n_in,
                              void* d_out, int out_size, void* d_ws,
                              size_t ws_size, hipStream_t stream) {
  const float* x      = (const float*)d_in[0];
  const float* dfe1_w = (const float*)d_in[1];
  const float* dse1_g = (const float*)d_in[2];
  const float* dse1_b = (const float*)d_in[3];
  const float* dse1_w = (const float*)d_in[4];
  const float* bn1_g  = (const float*)d_in[5];
  const float* bn1_b  = (const float*)d_in[6];
  const float* dfe2_w = (const float*)d_in[7];
  const float* dse2_g = (const float*)d_in[8];
  const float* dse2_b = (const float*)d_in[9];
  const float* dse2_w = (const float*)d_in[10];
  const float* bn2_g  = (const float*)d_in[11];
  const float* bn2_b  = (const float*)d_in[12];
  const float* fc1_w  = (const float*)d_in[13];
  const float* fc1_b  = (const float*)d_in[14];
  const float* fc2_w  = (const float*)d_in[15];
  const float* fc2_b  = (const float*)d_in[16];
  const float* fc3_w  = (const float*)d_in[17];
  const float* fc3_b  = (const float*)d_in[18];
  float* out = (float*)d_out;
  char* ws = (char*)d_ws;
  short* h1 = (short*)(ws + OFF_H1);
  f16* y1 = (f16*)(ws + OFF_Y1);
  float* y2 = (float*)(ws + OFF_Y2);
  short* h2 = (short*)(ws + OFF_H2);
  short* a1 = (short*)(ws + OFF_A1);
  float* a2 = (float*)(ws + OFF_A2);
  short* wb1 = (short*)(ws + OFF_WB1);
  short* wb2 = (short*)(ws + OFF_WB2);
  double* st = (double*)(ws + OFF_ST);
  double* ST1 = st;
  double* ST2 = st + (size_t)16 * 8;
  double* ST3 = st + (size_t)32 * 8;
  double* ST4 = st + (size_t)64 * 8;

  hipMemsetAsync(st, 0, 96 * 8 * sizeof(double), stream);
  k_cast_w<<<5120, 256, 0, stream>>>(fc1_w, fc2_w, wb1, wb2);
  k_conv1_y1<<<2048, 256, 0, stream>>>(x, dfe1_w, y1, ST1);
  k_xr1_stats<<<1024, 256, 0, stream>>>(y1, dse1_g, dse1_b, ST1, ST2);
  k_l1_out<<<1024, 256, 0, stream>>>(y1, dse1_g, dse1_b, dse1_w, bn1_g, bn1_b,
                                     ST1, ST2, h1);
  k_conv2_mfma<<<1024, 256, 0, stream>>>(h1, dfe2_w, y2, ST3);
  k_xr2_stats<<<4096, 256, 0, stream>>>(y2, dse2_g, dse2_b, ST3, ST4);
  k_l2_out<<<1024, 256, 0, stream>>>(y2, dse2_g, dse2_b, dse2_w, bn2_g, bn2_b,
                                     ST3, ST4, h2);
  k_fc_mfma<2048, 1, 1><<<dim3(8, 64), 256, 0, stream>>>(h2, wb1, fc1_b, a1);
  k_fc_mfma<512, 1, 0><<<dim3(8, 64), 256, 0, stream>>>(a1, wb2, fc2_b, a2);
  k_fc3<<<1024, 256, 0, stream>>>(a2, fc3_w, fc3_b, out);
}

// Round 7
// 390.156 us; speedup vs baseline: 1.1775x; 1.1775x over previous
//
#include <hip/hip_runtime.h>
#include <math.h>

#define EPS_BN 1e-5

namespace {

constexpr double CNT1 = 4096.0 * 1024.0;  // layer1 BN count: B*32*32
constexpr double CNT2 = 4096.0 * 256.0;   // layer2 BN count: B*16*16

// workspace layout (bytes). Required ws >= ~137 MiB.
constexpr size_t OFF_H1 = 0;            // [4096,256px,16ci] bf16 = 32 MiB
constexpr size_t OFF_Y1 = 67108864;     // [4096,1024px,8ch] f16 = 64 MiB (dies after l1_out)
constexpr size_t OFF_Y2 = 67108864;     // [4096,16,16,16] f32 = 64 MiB (aliases Y1)
constexpr size_t OFF_H2 = 0;            // [4096,2048] bf16 (reuses h1 after conv2)
constexpr size_t OFF_A1 = 33554432;     // [4096,512] bf16
constexpr size_t OFF_A2 = 41943040;     // [4096,512] f32
constexpr size_t OFF_ST = 134217728;    // BN stats: 96 slots x 64B
constexpr size_t OFF_WB1 = 134283264;   // fc1_w bf16 [512,2048] = 2 MiB
constexpr size_t OFF_WB2 = 136380416;   // fc2_w bf16 [512,512] = 0.5 MiB

#define STG(p, i) (p)[(size_t)(i) * 8]

typedef short bf16x8 __attribute__((ext_vector_type(8)));
typedef float f32x4 __attribute__((ext_vector_type(4)));
typedef _Float16 f16;
typedef _Float16 f16x8 __attribute__((ext_vector_type(8)));

__device__ __forceinline__ short f2bf(float f) {
  unsigned u = __float_as_uint(f);
  u = (u + 0x7fffu + ((u >> 16) & 1u)) >> 16;
  return (short)u;
}

__device__ __forceinline__ float wave_sum(float v) {
#pragma unroll
  for (int o = 32; o > 0; o >>= 1) v += __shfl_down(v, o, 64);
  return v;
}

template <int NV>
__device__ __forceinline__ void block_stats_atomic(const float* s, const float* q,
                                                   double* __restrict__ st) {
  __shared__ float red[4][NV * 2];
  const int lane = threadIdx.x & 63, wid = threadIdx.x >> 6;
#pragma unroll
  for (int c = 0; c < NV; ++c) {
    float sv = wave_sum(s[c]);
    float qv = wave_sum(q[c]);
    if (lane == 0) { red[wid][2 * c] = sv; red[wid][2 * c + 1] = qv; }
  }
  __syncthreads();
  if (threadIdx.x < NV * 2) {
    float v = red[0][threadIdx.x] + red[1][threadIdx.x] + red[2][threadIdx.x] +
              red[3][threadIdx.x];
    unsafeAtomicAdd(st + (size_t)threadIdx.x * 8, (double)v);
  }
}

// ---------------- layer 1: conv 3x3, 3->8, on 32x32, pad 1 -------------------
// x staged zero-padded into LDS [3][34 rows][36 cols] (row stride 36 floats for
// 16B-aligned vector reads); weights transposed wk[27tap][8co].
// Thread = 4 consecutive out pixels in one row: row rr=tid>>3, cols c0..c0+3,
// c0=(tid&7)*4. Window = 6 contiguous floats per (ci,row) -> b128+b64 reads.
// conv1 + raw-y1 stats + y1 f16 NHWC store [n][1024px][8ch].
// 2 images per block (sequential phases, single buffer), grid 2048.
__global__ __launch_bounds__(256) void k_conv1_y1(
    const float* __restrict__ x, const float* __restrict__ w1,
    f16* __restrict__ y1, double* __restrict__ st1) {
  __shared__ __align__(16) float xs[3 * 1224];  // 3 x 34 x 36
  __shared__ __align__(16) float wk[216];
  const int tid = threadIdx.x;
  for (int i = tid; i < 3 * 1224; i += 256) xs[i] = 0.f;
  if (tid < 216) wk[(tid % 27) * 8 + tid / 27] = w1[tid];
  const int rr = tid >> 3, c0 = (tid & 7) * 4;
  const int n0 = blockIdx.x * 2;
  float s[8], q[8];
#pragma unroll
  for (int c = 0; c < 8; ++c) { s[c] = 0.f; q[c] = 0.f; }
  for (int img = 0; img < 2; ++img) {
    __syncthreads();
    {
      const float* xp = x + (size_t)(n0 + img) * 3072;
      for (int i = tid; i < 3072; i += 256) {
        int ci = i >> 10, r = (i >> 5) & 31, c = i & 31;
        xs[ci * 1224 + (r + 1) * 36 + (c + 1)] = xp[i];
      }
    }
    __syncthreads();
    float acc[4][8];
#pragma unroll
    for (int p = 0; p < 4; ++p)
#pragma unroll
      for (int co = 0; co < 8; ++co) acc[p][co] = 0.f;
#pragma unroll
    for (int ci = 0; ci < 3; ++ci)
#pragma unroll
      for (int dy = 0; dy < 3; ++dy) {
        const float* rowp = &xs[ci * 1224 + (rr + dy) * 36 + c0];
        float xw[6];
        *(float4*)&xw[0] = *(const float4*)rowp;
        *(float2*)&xw[4] = *(const float2*)(rowp + 4);
#pragma unroll
        for (int dx = 0; dx < 3; ++dx) {
          const int j = ci * 9 + dy * 3 + dx;
          float wv[8];
          *(float4*)&wv[0] = *(const float4*)&wk[j * 8];
          *(float4*)&wv[4] = *(const float4*)&wk[j * 8 + 4];
#pragma unroll
          for (int p = 0; p < 4; ++p)
#pragma unroll
            for (int co = 0; co < 8; ++co) acc[p][co] += xw[p + dx] * wv[co];
        }
      }
    f16* yp = &y1[((size_t)(n0 + img) * 1024 + rr * 32 + c0) * 8];
#pragma unroll
    for (int p = 0; p < 4; ++p) {
      f16 hv8[8];
#pragma unroll
      for (int co = 0; co < 8; ++co) {
        float v = acc[p][co];
        s[co] += v; q[co] += v * v;
        hv8[co] = (f16)v;
      }
      *(uint4*)&yp[p * 8] = *(uint4*)hv8;
    }
  }
  block_stats_atomic<8>(s, q, st1);
}

// xr1 = relu(bn1(y1)) stats; grid-strided NHWC streaming, grid 1024.
__global__ __launch_bounds__(256) void k_xr1_stats(
    const f16* __restrict__ y1, const float* __restrict__ g1,
    const float* __restrict__ b1, const double* __restrict__ st1,
    double* __restrict__ st2) {
  float a1[8], c1[8];
#pragma unroll
  for (int c = 0; c < 8; ++c) {
    double sd = STG(st1, 2 * c), qd = STG(st1, 2 * c + 1);
    double md = sd / CNT1;
    float inv = (float)(1.0 / sqrt(qd / CNT1 - md * md + (double)EPS_BN));
    a1[c] = inv * g1[c];
    c1[c] = b1[c] - (float)md * a1[c];
  }
  const size_t base = (size_t)blockIdx.x * 4096 + threadIdx.x;
  float s[8], q[8];
#pragma unroll
  for (int c = 0; c < 8; ++c) { s[c] = 0.f; q[c] = 0.f; }
#pragma unroll
  for (int k = 0; k < 16; ++k) {
    f16x8 v = *(const f16x8*)&y1[(base + (size_t)k * 256) * 8];
#pragma unroll
    for (int c = 0; c < 8; ++c) {
      float xr = fmaxf((float)v[c] * a1[c] + c1[c], 0.f);
      s[c] += xr; q[c] += xr * xr;
    }
  }
  block_stats_atomic<8>(s, q, st2);
}

// y1 NHWC -> BN1+relu -> scale-expand -> BN2+relu -> 2x2 maxpool
// -> h1 bf16 NHWC [img][256px][16c]. 4 images per block, grid 1024.
__global__ __launch_bounds__(256) void k_l1_out(
    const f16* __restrict__ y1, const float* __restrict__ g1,
    const float* __restrict__ b1, const float* __restrict__ dsew,
    const float* __restrict__ bng, const float* __restrict__ bnb,
    const double* __restrict__ st1, const double* __restrict__ st2,
    short* __restrict__ h1) {
  __shared__ float cA1[8], cC1[8], cS2[16], cO2[16];
  const int tid = threadIdx.x;
  if (tid < 16) {
    const int i = tid >> 1, g = tid & 1;
    double sd = STG(st1, 2 * i), qd = STG(st1, 2 * i + 1);
    double md = sd / CNT1;
    float inv1 = (float)(1.0 / sqrt(qd / CNT1 - md * md + (double)EPS_BN));
    float a1 = inv1 * g1[i];
    if (g == 0) { cA1[i] = a1; cC1[i] = b1[i] - (float)md * a1; }
    double s2 = STG(st2, 2 * i), q2 = STG(st2, 2 * i + 1);
    double mx = s2 / CNT1, vx = q2 / CNT1 - mx * mx;
    float w = dsew[i * 2 + g];
    double inv2 = 1.0 / sqrt((double)w * w * vx + (double)EPS_BN);
    cS2[tid] = (float)(w * inv2) * bng[tid];
    cO2[tid] = bnb[tid] - (float)(w * mx * inv2) * bng[tid];
  }
  __syncthreads();
  const int sub = tid >> 6, lane = tid & 63;
  const int n = blockIdx.x * 4 + sub;
#pragma unroll
  for (int w = 0; w < 4; ++w) {
    const int opx = w * 64 + lane, oy = opx >> 4, ox = opx & 15;
    const size_t pbase = ((size_t)n * 1024 + (size_t)(2 * oy) * 32 + 2 * ox) * 8;
    f16x8 vA = *(const f16x8*)&y1[pbase];
    f16x8 vB = *(const f16x8*)&y1[pbase + 8];
    f16x8 vC = *(const f16x8*)&y1[pbase + 256];
    f16x8 vD = *(const f16x8*)&y1[pbase + 264];
    short hv[16];
#pragma unroll
    for (int i = 0; i < 8; ++i) {
      float a1 = cA1[i], c1 = cC1[i];
      float xr0 = fmaxf((float)vA[i] * a1 + c1, 0.f);
      float xr1 = fmaxf((float)vB[i] * a1 + c1, 0.f);
      float xr2 = fmaxf((float)vC[i] * a1 + c1, 0.f);
      float xr3 = fmaxf((float)vD[i] * a1 + c1, 0.f);
#pragma unroll
      for (int g = 0; g < 2; ++g) {
        const int c = 2 * i + g;
        float sc = cS2[c], of = cO2[c];
        float r0 = fmaxf(xr0 * sc + of, 0.f);
        float r1 = fmaxf(xr1 * sc + of, 0.f);
        float r2 = fmaxf(xr2 * sc + of, 0.f);
        float r3 = fmaxf(xr3 * sc + of, 0.f);
        hv[c] = f2bf(fmaxf(fmaxf(r0, r1), fmaxf(r2, r3)));
      }
    }
    uint4* dst = (uint4*)&h1[((size_t)n * 256 + opx) * 16];
    dst[0] = ((uint4*)hv)[0];
    dst[1] = ((uint4*)hv)[1];
  }
}

// ---------------- layer 2 conv via MFMA ---------------------------------
// 4 images staged per iter, 2 iters (8 images/block), grid 512 (2 blocks/CU).
__global__ __launch_bounds__(256) void k_conv2_mfma(
    const short* __restrict__ h1, const float* __restrict__ w2,
    float* __restrict__ y2, double* __restrict__ st3) {
  __shared__ short smem[4 * 5184 + 10 * 256];
  __shared__ float red[4][32];
  short* hs = smem;                 // 4 padded images
  short* wt = smem + 4 * 5184;      // [10][16co][16ci], slot 9 stays zero
  const int tid = threadIdx.x, wid = tid >> 6, lane = tid & 63;
  for (int i = tid; i < (4 * 5184 + 10 * 256) / 2; i += 256) ((int*)smem)[i] = 0;
  __syncthreads();
  for (int i = tid; i < 2304; i += 256) {
    const int s = i >> 8, co = (i >> 4) & 15, ci = i & 15;
    wt[i] = f2bf(w2[(co * 16 + ci) * 9 + s]);
  }
  const int c = lane & 15, quad = lane >> 4;
  const int ci0 = (quad & 1) * 8;
  int aoff[5];
#pragma unroll
  for (int p = 0; p < 5; ++p) {
    int s = 2 * p + (quad >> 1);
    if (s > 8) s = 8;  // address clamp; B-frag for that k-half is zero
    const int dy = s / 3, dx = s % 3;
    aoff[p] = (dy * 18 + (c + dx)) * 16 + ci0;
  }
  float ssum = 0.f, qsum = 0.f;
  for (int it = 0; it < 2; ++it) {
    __syncthreads();
    {  // stage 4 images (interior only; borders stay zero)
      const uint4* src =
          (const uint4*)(h1 + ((size_t)blockIdx.x * 8 + it * 4) * 4096);
      for (int ch = tid; ch < 2048; ch += 256) {
        const int im = ch >> 9, j = ch & 511, px = j >> 1, half = j & 1;
        const int r = px >> 4, cc = px & 15;
        *(uint4*)&hs[im * 5184 + ((r + 1) * 18 + (cc + 1)) * 16 + half * 8] =
            src[ch];
      }
    }
    __syncthreads();
    bf16x8 bf[5];
#pragma unroll
    for (int p = 0; p < 5; ++p) {
      const int s = 2 * p + (quad >> 1);  // s==9 -> wt slot 9 == zeros
      bf[p] = *(const bf16x8*)&wt[s * 256 + c * 16 + ci0];
    }
    const short* hbase = hs + wid * 5184;
    const int img = blockIdx.x * 8 + it * 4 + wid;
    float* yp = y2 + ((size_t)img * 16 + c) * 256 + quad * 4;
    for (int r = 0; r < 16; ++r) {
      f32x4 acc = {0.f, 0.f, 0.f, 0.f};
#pragma unroll
      for (int p = 0; p < 5; ++p) {
        bf16x8 a = *(const bf16x8*)&hbase[r * 288 + aoff[p]];
        acc = __builtin_amdgcn_mfma_f32_16x16x32_bf16(a, bf[p], acc, 0, 0, 0);
      }
      *(float4*)&yp[r * 16] = *(float4*)&acc;
#pragma unroll
      for (int g = 0; g < 4; ++g) { float v = acc[g]; ssum += v; qsum += v * v; }
    }
  }
  // lanes {l, l+16, l+32, l+48} share co = l&15
  ssum += __shfl_down(ssum, 32, 64); ssum += __shfl_down(ssum, 16, 64);
  qsum += __shfl_down(qsum, 32, 64); qsum += __shfl_down(qsum, 16, 64);
  if (lane < 16) { red[wid][lane] = ssum; red[wid][16 + lane] = qsum; }
  __syncthreads();
  if (tid < 32) {
    const int cc = tid & 15, isq = tid >> 4;
    float v = red[0][isq * 16 + cc] + red[1][isq * 16 + cc] +
              red[2][isq * 16 + cc] + red[3][isq * 16 + cc];
    unsafeAtomicAdd(st3 + (size_t)(2 * cc + isq) * 8, (double)v);
  }
}

__global__ __launch_bounds__(256) void k_xr2_stats(
    const float* __restrict__ y2, const float* __restrict__ g2,
    const float* __restrict__ b2, const double* __restrict__ st3,
    double* __restrict__ st4) {
  const int c = blockIdx.x & 15, n0 = (blockIdx.x >> 4) << 4;
  double sd = STG(st3, 2 * c), qd = STG(st3, 2 * c + 1);
  double md = sd / CNT2;
  float m = (float)md;
  float inv = (float)(1.0 / sqrt(qd / CNT2 - md * md + (double)EPS_BN));
  float gg = g2[c], bb = b2[c];
  float s = 0.f, q = 0.f;
#pragma unroll
  for (int k = 0; k < 16; ++k) {
    float v = y2[((size_t)(n0 + k) * 16 + c) * 256 + threadIdx.x];
    float xr = fmaxf((v - m) * inv * gg + bb, 0.f);
    s += xr; q += xr * xr;
  }
  block_stats_atomic<1>(&s, &q, st4 + (size_t)(2 * c) * 8);
}

// y2 -> BN+relu -> scale-expand -> BN+relu -> 2x2 maxpool -> h2 bf16 [4096,2048]
__global__ __launch_bounds__(256) void k_l2_out(
    const float* __restrict__ y2, const float* __restrict__ g2,
    const float* __restrict__ b2, const float* __restrict__ dsew,
    const float* __restrict__ bng, const float* __restrict__ bnb,
    const double* __restrict__ st3, const double* __restrict__ st4,
    short* __restrict__ h2) {
  __shared__ float cS3[16], cO3[16], cS4[32], cO4[32];
  const int tid = threadIdx.x;
  if (tid < 32) {
    const int i = tid >> 1, g = tid & 1;
    double sd = STG(st3, 2 * i), qd = STG(st3, 2 * i + 1);
    double md = sd / CNT2;
    float inv3 = (float)(1.0 / sqrt(qd / CNT2 - md * md + (double)EPS_BN));
    float a3 = inv3 * g2[i];
    if (g == 0) { cS3[i] = a3; cO3[i] = b2[i] - (float)md * a3; }
    double s4 = STG(st4, 2 * i), q4 = STG(st4, 2 * i + 1);
    double mx = s4 / CNT2, vx = q4 / CNT2 - mx * mx;
    float w = dsew[2 * i + g];
    double inv4 = 1.0 / sqrt((double)w * w * vx + (double)EPS_BN);
    cS4[tid] = (float)(w * inv4) * bng[tid];
    cO4[tid] = bnb[tid] - (float)(w * mx * inv4) * bng[tid];
  }
  __syncthreads();
  const int sub = tid >> 6, lane = tid & 63;
  const int n = blockIdx.x * 4 + sub;
  const int px = lane & 7, py = lane >> 3;
#pragma unroll
  for (int i = 0; i < 16; ++i) {
    const size_t base = ((size_t)n * 16 + i) * 256;
    float2 v01 = *(const float2*)&y2[base + (2 * py) * 16 + 2 * px];
    float2 v23 = *(const float2*)&y2[base + (2 * py + 1) * 16 + 2 * px];
    float a3 = cS3[i], c3 = cO3[i];
    float xr0 = fmaxf(v01.x * a3 + c3, 0.f);
    float xr1 = fmaxf(v01.y * a3 + c3, 0.f);
    float xr2 = fmaxf(v23.x * a3 + c3, 0.f);
    float xr3 = fmaxf(v23.y * a3 + c3, 0.f);
#pragma unroll
    for (int g = 0; g < 2; ++g) {
      const int c = 2 * i + g;
      float sc = cS4[c], of = cO4[c];
      float r0 = fmaxf(xr0 * sc + of, 0.f);
      float r1 = fmaxf(xr1 * sc + of, 0.f);
      float r2 = fmaxf(xr2 * sc + of, 0.f);
      float r3 = fmaxf(xr3 * sc + of, 0.f);
      h2[(size_t)n * 2048 + c * 64 + py * 8 + px] =
          f2bf(fmaxf(fmaxf(r0, r1), fmaxf(r2, r3)));
    }
  }
}

// cast fc1_w (512x2048) and fc2_w (512x512) to bf16
__global__ __launch_bounds__(256) void k_cast_w(const float* __restrict__ w1,
                                                const float* __restrict__ w2,
                                                short* __restrict__ o1,
                                                short* __restrict__ o2) {
  const int i = blockIdx.x * 256 + threadIdx.x;
  if (i < 1048576) o1[i] = f2bf(w1[i]);
  else o2[i - 1048576] = f2bf(w2[i - 1048576]);
}

// ------------- FC via MFMA: C[M,512] = act(A[M,K]bf16 @ W[512,K]bf16^T + b) --
template <int K, int RELU, int OUT_BF16>
__global__ __launch_bounds__(256) void k_fc_mfma(
    const short* __restrict__ A, const short* __restrict__ W,
    const float* __restrict__ bias, void* __restrict__ Cv) {
  const int wv = threadIdx.x >> 6, lane = threadIdx.x & 63;
  const int bm = blockIdx.y * 64;
  const int bn = blockIdx.x * 64 + wv * 16;
  const int cl = lane & 15, quad = lane >> 4;
  const short* ap = A + (size_t)(bm + cl) * K + quad * 8;
  const short* bp = W + (size_t)(bn + cl) * K + quad * 8;
  f32x4 acc0 = {0.f, 0.f, 0.f, 0.f}, acc1 = acc0, acc2 = acc0, acc3 = acc0;
#pragma unroll 4
  for (int k0 = 0; k0 < K; k0 += 32) {
    bf16x8 b = *(const bf16x8*)bp;
    bf16x8 a0 = *(const bf16x8*)ap;
    bf16x8 a1 = *(const bf16x8*)(ap + (size_t)16 * K);
    bf16x8 a2 = *(const bf16x8*)(ap + (size_t)32 * K);
    bf16x8 a3 = *(const bf16x8*)(ap + (size_t)48 * K);
    ap += 32; bp += 32;
    acc0 = __builtin_amdgcn_mfma_f32_16x16x32_bf16(a0, b, acc0, 0, 0, 0);
    acc1 = __builtin_amdgcn_mfma_f32_16x16x32_bf16(a1, b, acc1, 0, 0, 0);
    acc2 = __builtin_amdgcn_mfma_f32_16x16x32_bf16(a2, b, acc2, 0, 0, 0);
    acc3 = __builtin_amdgcn_mfma_f32_16x16x32_bf16(a3, b, acc3, 0, 0, 0);
  }
  const float bia = bias[bn + cl];
  f32x4 av[4] = {acc0, acc1, acc2, acc3};
#pragma unroll
  for (int rt = 0; rt < 4; ++rt) {
#pragma unroll
    for (int r = 0; r < 4; ++r) {
      const int row = bm + rt * 16 + quad * 4 + r;
      float v = av[rt][r] + bia;
      if (RELU) v = fmaxf(v, 0.f);
      if (OUT_BF16)
        ((short*)Cv)[(size_t)row * 512 + bn + cl] = f2bf(v);
      else
        ((float*)Cv)[(size_t)row * 512 + bn + cl] = v;
    }
  }
}

// fc3: one wave per row, N=10, K=512, fp32
__global__ __launch_bounds__(256) void k_fc3(const float* __restrict__ A,
                                             const float* __restrict__ W,
                                             const float* __restrict__ b,
                                             float* __restrict__ out) {
  const int wid = threadIdx.x >> 6, lane = threadIdx.x & 63;
  const int row = blockIdx.x * 4 + wid;
  float p[10];
#pragma unroll
  for (int o = 0; o < 10; ++o) p[o] = 0.f;
  const float* a = A + (size_t)row * 512;
#pragma unroll
  for (int jj = 0; jj < 8; ++jj) {
    const int j = lane + jj * 64;
    float av = a[j];
#pragma unroll
    for (int o = 0; o < 10; ++o) p[o] += av * W[o * 512 + j];
  }
#pragma unroll
  for (int o = 0; o < 10; ++o) p[o] = wave_sum(p[o]);
  if (lane == 0) {
#pragma unroll
    for (int o = 0; o < 10; ++o) out[(size_t)row * 10 + o] = p[o] + b[o];
  }
}

}  // namespace

extern "C" void kernel_launch(void* const* d_in, const int* in_sizes, int n_in,
                              void* d_out, int out_size, void* d_ws,
                              size_t ws_size, hipStream_t stream) {
  const float* x      = (const float*)d_in[0];
  const float* dfe1_w = (const float*)d_in[1];
  const float* dse1_g = (const float*)d_in[2];
  const float* dse1_b = (const float*)d_in[3];
  const float* dse1_w = (const float*)d_in[4];
  const float* bn1_g  = (const float*)d_in[5];
  const float* bn1_b  = (const float*)d_in[6];
  const float* dfe2_w = (const float*)d_in[7];
  const float* dse2_g = (const float*)d_in[8];
  const float* dse2_b = (const float*)d_in[9];
  const float* dse2_w = (const float*)d_in[10];
  const float* bn2_g  = (const float*)d_in[11];
  const float* bn2_b  = (const float*)d_in[12];
  const float* fc1_w  = (const float*)d_in[13];
  const float* fc1_b  = (const float*)d_in[14];
  const float* fc2_w  = (const float*)d_in[15];
  const float* fc2_b  = (const float*)d_in[16];
  const float* fc3_w  = (const float*)d_in[17];
  const float* fc3_b  = (const float*)d_in[18];
  float* out = (float*)d_out;
  char* ws = (char*)d_ws;
  short* h1 = (short*)(ws + OFF_H1);
  f16* y1 = (f16*)(ws + OFF_Y1);
  float* y2 = (float*)(ws + OFF_Y2);
  short* h2 = (short*)(ws + OFF_H2);
  short* a1 = (short*)(ws + OFF_A1);
  float* a2 = (float*)(ws + OFF_A2);
  short* wb1 = (short*)(ws + OFF_WB1);
  short* wb2 = (short*)(ws + OFF_WB2);
  double* st = (double*)(ws + OFF_ST);
  double* ST1 = st;
  double* ST2 = st + (size_t)16 * 8;
  double* ST3 = st + (size_t)32 * 8;
  double* ST4 = st + (size_t)64 * 8;

  hipMemsetAsync(st, 0, 96 * 8 * sizeof(double), stream);
  k_cast_w<<<5120, 256, 0, stream>>>(fc1_w, fc2_w, wb1, wb2);
  k_conv1_y1<<<2048, 256, 0, stream>>>(x, dfe1_w, y1, ST1);
  k_xr1_stats<<<1024, 256, 0, stream>>>(y1, dse1_g, dse1_b, ST1, ST2);
  k_l1_out<<<1024, 256, 0, stream>>>(y1, dse1_g, dse1_b, dse1_w, bn1_g, bn1_b,
                                     ST1, ST2, h1);
  k_conv2_mfma<<<512, 256, 0, stream>>>(h1, dfe2_w, y2, ST3);
  k_xr2_stats<<<4096, 256, 0, stream>>>(y2, dse2_g, dse2_b, ST3, ST4);
  k_l2_out<<<1024, 256, 0, stream>>>(y2, dse2_g, dse2_b, dse2_w, bn2_g, bn2_b,
                                     ST3, ST4, h2);
  k_fc_mfma<2048, 1, 1><<<dim3(8, 64), 256, 0, stream>>>(h2, wb1, fc1_b, a1);
  k_fc_mfma<512, 1, 0><<<dim3(8, 64), 256, 0, stream>>>(a1, wb2, fc2_b, a2);
  k_fc3<<<1024, 256, 0, stream>>>(a2, fc3_w, fc3_b, out);
}